// Round 13
// baseline (210.401 us; speedup 1.0000x reference)
//
#include <hip/hip_runtime.h>
#include <hip/hip_bf16.h>

#define N_NODES 100000
#define N_EDGES 800000
#define D 64
#define SLICES 64                 // edge slices
#define HIST_BLOCKS (SLICES * 2)  // x2 node-range halves
#define NHALF 50000               // nodes per half
#define HWORDS_H 12500            // u8-packed words per half (50 KB LDS)
#define QUADS (N_EDGES / 4)       // 200000 quad-edge groups
#define QPS (QUADS / SLICES)      // 3125 quads per slice

// ---------------------------------------------------------------------------
// MEASUREMENT ROUND (R13): identical to R12 except proj_kernel is launched
// 8x (idempotent). P = (dur_us - 37.9) / 7. Two consecutive proj
// mispredictions (R8 neutral, R12 -2 vs -10 predicted) => the G/H/P
// decomposition must be re-measured before any further optimization.
// Amplified proj also lifts its eager duration above the 38.7us harness-
// fill cutoff, restoring counter visibility next round if needed.
//
// softmax(axis=1) over [E,1] == 1.0 identically, so
//   z[n] = count[n] * (node_features[n] @ W_n^T + b_n)
// ---------------------------------------------------------------------------

__global__ __launch_bounds__(1024) void hist_kernel(
        const int* __restrict__ idx32,   // [2, N_EDGES] int64 or int32
        unsigned*  __restrict__ part) {  // [HIST_BLOCKS][HWORDS_H]
    __shared__ __align__(16) unsigned h[HWORDS_H];  // 50 KB, u8-packed
    uint4* __restrict__ h4 = (uint4*)h;
    for (int i = threadIdx.x; i < HWORDS_H / 4; i += 1024)
        h4[i] = uint4{0u, 0u, 0u, 0u};

    // int64/int32 detection: for LE int64 values in [0,N_NODES) all odd
    // int32 words are 0. Each wave samples 256 odd words; ballot-OR.
    const int lane = threadIdx.x & 63;
    int s = 0;
#pragma unroll
    for (int k = 0; k < 4; ++k) s |= idx32[2 * (lane + 64 * k) + 1];
    const bool is64 = (__ballot(s != 0) == 0ULL);  // wave-uniform

    __syncthreads();

    const int slice = blockIdx.x >> 1;
    const int half  = blockIdx.x & 1;
    const int base  = half * NHALF;

    // 4 edges per iteration, vectorized loads. Count only our half-range.
    for (int t = slice * QPS + threadIdx.x; t < (slice + 1) * QPS; t += 1024) {
        int v[4];
        if (is64) {
            const int4 a = ((const int4*)idx32)[2 * t + 0];  // edges 4t,4t+1
            const int4 b = ((const int4*)idx32)[2 * t + 1];  // edges 4t+2,+3
            v[0] = a.x; v[1] = a.z; v[2] = b.x; v[3] = b.z;
        } else {
            const int4 a = ((const int4*)idx32)[t];
            v[0] = a.x; v[1] = a.y; v[2] = a.z; v[3] = a.w;
        }
#pragma unroll
        for (int j = 0; j < 4; ++j) {
            const unsigned u = (unsigned)(v[j] - base);
            if (u < (unsigned)NHALF)
                atomicAdd(&h[u >> 2], 1u << (8 * (u & 3)));  // LDS atomic
        }
    }

    __syncthreads();

    // stream partial to global, 16B stores (HWORDS_H/4 = 3125 uint4)
    uint4* __restrict__ dst = (uint4*)(part + blockIdx.x * HWORDS_H);
    for (int i = threadIdx.x; i < HWORDS_H / 4; i += 1024) dst[i] = h4[i];
}

// Block = 256 threads = 4 waves; block handles 64 nodes.
//   lane (tid & 63) -> OUTPUT o; wave wv -> nodes [16wv, 16wv+16).
// W[o][*] lives in 64 VGPRs per lane (no scalar loads in hot loop);
// x via uniform LDS broadcast; stores row-contiguous.
__global__ __launch_bounds__(256, 4) void proj_kernel(
        const float* __restrict__ nf,       // [N_NODES, 64]
        const float* __restrict__ Wn,       // [64, 64] row-major
        const float* __restrict__ bn,       // [64]
        const unsigned* __restrict__ part,  // [HIST_BLOCKS][HWORDS_H]
        float* __restrict__ out) {          // [N_NODES, 64]
    __shared__ __align__(16) float xs[64 * 64];  // [node][i], 16 KB
    __shared__ float wl[64 * 65];                // W rows, +1 pad -> no conflict
    __shared__ unsigned cnt_p[4][64];            // merge-fold partials

    const int t = threadIdx.x;
    const int base = blockIdx.x * 64;
    const int lane = t & 63;
    const int wv = __builtin_amdgcn_readfirstlane(t >> 6);  // 0..3

    // ---- stage x tile: coalesced global float4 -> linear LDS ----
#pragma unroll
    for (int i = 0; i < 4; ++i) {
        const int r = i * 16 + (t >> 4);               // row 0..63
        const int node = min(base + r, N_NODES - 1);   // clamp tail
        const float4 v = *reinterpret_cast<const float4*>(
            nf + (size_t)node * D + (t & 15) * 4);
        *reinterpret_cast<float4*>(&xs[r * 64 + (t & 15) * 4]) = v;
    }

    // ---- stage W: coalesced global -> padded LDS (bank = (r+i)&31) ----
    {
        const int r = t >> 2;          // 0..63
        const int c0 = (t & 3) * 16;   // 0,16,32,48
#pragma unroll
        for (int k = 0; k < 4; ++k) {
            const float4 v = *reinterpret_cast<const float4*>(
                Wn + r * D + c0 + k * 4);
            wl[r * 65 + c0 + k * 4 + 0] = v.x;
            wl[r * 65 + c0 + k * 4 + 1] = v.y;
            wl[r * 65 + c0 + k * 4 + 2] = v.z;
            wl[r * 65 + c0 + k * 4 + 3] = v.w;
        }
    }

    // ---- merge-fold: wave wv sums slice-partials [16wv,16wv+16) for its
    //      lane's node (clamped on tail; unused there). ----
    {
        const int node = min(base + lane, N_NODES - 1);
        const int half = (node >= NHALF) ? 1 : 0;
        const int lw = (node - half * NHALF) >> 2;
        const int sh = 8 * (node & 3);
        unsigned s = 0;
#pragma unroll
        for (int k = 0; k < 16; ++k) {
            const int b = 16 * wv + k;  // slice
            s += (part[(size_t)(2 * b + half) * HWORDS_H + lw] >> sh) & 255u;
        }
        cnt_p[wv][lane] = s;
    }

    __syncthreads();

    // ---- compute ----
    const float blane = bn[lane];  // coalesced, once

    float wr[64];  // this lane's W row, conflict-free LDS read (pad 65)
#pragma unroll
    for (int i = 0; i < 64; ++i) wr[i] = wl[lane * 65 + i];

#pragma unroll
    for (int g = 0; g < 4; ++g) {
        const int nA = wv * 16 + g * 4;  // first of 4 nodes this group
        const float* __restrict__ x0 = &xs[(nA + 0) * 64];
        const float* __restrict__ x1 = &xs[(nA + 1) * 64];
        const float* __restrict__ x2 = &xs[(nA + 2) * 64];
        const float* __restrict__ x3 = &xs[(nA + 3) * 64];
        float a0 = blane, a1 = blane, a2 = blane, a3 = blane;
#pragma unroll
        for (int q = 0; q < 16; ++q) {  // uniform b128 broadcasts
            const float4 v0 = *reinterpret_cast<const float4*>(x0 + q * 4);
            const float4 v1 = *reinterpret_cast<const float4*>(x1 + q * 4);
            const float4 v2 = *reinterpret_cast<const float4*>(x2 + q * 4);
            const float4 v3 = *reinterpret_cast<const float4*>(x3 + q * 4);
            a0 = fmaf(v0.x, wr[q * 4 + 0], a0);
            a0 = fmaf(v0.y, wr[q * 4 + 1], a0);
            a0 = fmaf(v0.z, wr[q * 4 + 2], a0);
            a0 = fmaf(v0.w, wr[q * 4 + 3], a0);
            a1 = fmaf(v1.x, wr[q * 4 + 0], a1);
            a1 = fmaf(v1.y, wr[q * 4 + 1], a1);
            a1 = fmaf(v1.z, wr[q * 4 + 2], a1);
            a1 = fmaf(v1.w, wr[q * 4 + 3], a1);
            a2 = fmaf(v2.x, wr[q * 4 + 0], a2);
            a2 = fmaf(v2.y, wr[q * 4 + 1], a2);
            a2 = fmaf(v2.z, wr[q * 4 + 2], a2);
            a2 = fmaf(v2.w, wr[q * 4 + 3], a2);
            a3 = fmaf(v3.x, wr[q * 4 + 0], a3);
            a3 = fmaf(v3.y, wr[q * 4 + 1], a3);
            a3 = fmaf(v3.z, wr[q * 4 + 2], a3);
            a3 = fmaf(v3.w, wr[q * 4 + 3], a3);
        }
        // counts (uniform LDS reads) + row-contiguous stores
        const float c0f = (float)(cnt_p[0][nA + 0] + cnt_p[1][nA + 0] +
                                  cnt_p[2][nA + 0] + cnt_p[3][nA + 0]);
        const float c1f = (float)(cnt_p[0][nA + 1] + cnt_p[1][nA + 1] +
                                  cnt_p[2][nA + 1] + cnt_p[3][nA + 1]);
        const float c2f = (float)(cnt_p[0][nA + 2] + cnt_p[1][nA + 2] +
                                  cnt_p[2][nA + 2] + cnt_p[3][nA + 2]);
        const float c3f = (float)(cnt_p[0][nA + 3] + cnt_p[1][nA + 3] +
                                  cnt_p[2][nA + 3] + cnt_p[3][nA + 3]);
        const int nodeA = base + nA;
        if (nodeA + 0 < N_NODES) out[(size_t)(nodeA + 0) * D + lane] = c0f * a0;
        if (nodeA + 1 < N_NODES) out[(size_t)(nodeA + 1) * D + lane] = c1f * a1;
        if (nodeA + 2 < N_NODES) out[(size_t)(nodeA + 2) * D + lane] = c2f * a2;
        if (nodeA + 3 < N_NODES) out[(size_t)(nodeA + 3) * D + lane] = c3f * a3;
    }
}

extern "C" void kernel_launch(void* const* d_in, const int* in_sizes, int n_in,
                              void* d_out, int out_size, void* d_ws, size_t ws_size,
                              hipStream_t stream) {
    const float* nf   = (const float*)d_in[0];  // [100000, 64]
    const int*   eidx = (const int*)d_in[1];    // [2, 800000] int64 or int32
    const float* Wn   = (const float*)d_in[3];  // [64, 64]
    const float* bn   = (const float*)d_in[4];  // [64]
    float* out = (float*)d_out;                 // [100000, 64] f32

    unsigned* part = (unsigned*)d_ws;  // 6.4 MB of slice-partials

    hist_kernel<<<HIST_BLOCKS, 1024, 0, stream>>>(eidx, part);

    // AMPLIFICATION x8: identical, idempotent launches. P = (dur - 37.9)/7.
    for (int rep = 0; rep < 8; ++rep) {
        proj_kernel<<<(N_NODES + 63) / 64, 256, 0, stream>>>(
            nf, Wn, bn, part, out);
    }
}

// Round 14
// 42.621 us; speedup vs baseline: 4.9365x; 4.9365x over previous
//
#include <hip/hip_runtime.h>
#include <hip/hip_bf16.h>

#define N_NODES 100000
#define N_EDGES 800000
#define D 64
#define SLICES 64                 // edge slices
#define HIST_BLOCKS (SLICES * 2)  // x2 node-range halves
#define NHALF 50000               // nodes per half
#define HWORDS_H 12500            // u8-packed words per half (50 KB LDS)
#define QUADS (N_EDGES / 4)       // 200000 quad-edge groups
#define QPS (QUADS / SLICES)      // 3125 quads per slice

// ---------------------------------------------------------------------------
// softmax(axis=1) over [E,1] == 1.0 identically, so
//   z[n] = count[n] * (node_features[n] @ W_n^T + b_n)
// where count[n] = #edges with node0_idx == n. Attention branch is dead code.
//
// Proj v5 (R14): R13 measured P=24.6us and back-solved the LDS-broadcast
// cost: wave-uniform ds_read_b128 x-broadcasts = 256 LDS-pipe instrs/wave
// ~8-12cyc each on the per-CU (shared) LDS pipe ~= 21us/CU >> 5.2us VALU.
// Fix: x read DIRECTLY from global with wave-uniform addresses -> each load
// coalesces to ONE 16B transaction (same-segment degenerate case), L1/L2
// served, no x staging, no LDS-pipe involvement. W stays in VGPRs (LDS
// pad-68 roundtrip, conflict-free b128s). Same total nf bytes (25.6MB).
// ---------------------------------------------------------------------------

__global__ __launch_bounds__(1024) void hist_kernel(
        const int* __restrict__ idx32,   // [2, N_EDGES] int64 or int32
        unsigned*  __restrict__ part) {  // [HIST_BLOCKS][HWORDS_H]
    __shared__ __align__(16) unsigned h[HWORDS_H];  // 50 KB, u8-packed
    uint4* __restrict__ h4 = (uint4*)h;
    for (int i = threadIdx.x; i < HWORDS_H / 4; i += 1024)
        h4[i] = uint4{0u, 0u, 0u, 0u};

    // int64/int32 detection: for LE int64 values in [0,N_NODES) all odd
    // int32 words are 0. Each wave samples 256 odd words; ballot-OR.
    const int lane = threadIdx.x & 63;
    int s = 0;
#pragma unroll
    for (int k = 0; k < 4; ++k) s |= idx32[2 * (lane + 64 * k) + 1];
    const bool is64 = (__ballot(s != 0) == 0ULL);  // wave-uniform

    __syncthreads();

    const int slice = blockIdx.x >> 1;
    const int half  = blockIdx.x & 1;
    const int base  = half * NHALF;

    // 4 edges per iteration, vectorized loads. Count only our half-range.
    for (int t = slice * QPS + threadIdx.x; t < (slice + 1) * QPS; t += 1024) {
        int v[4];
        if (is64) {
            const int4 a = ((const int4*)idx32)[2 * t + 0];  // edges 4t,4t+1
            const int4 b = ((const int4*)idx32)[2 * t + 1];  // edges 4t+2,+3
            v[0] = a.x; v[1] = a.z; v[2] = b.x; v[3] = b.z;
        } else {
            const int4 a = ((const int4*)idx32)[t];
            v[0] = a.x; v[1] = a.y; v[2] = a.z; v[3] = a.w;
        }
#pragma unroll
        for (int j = 0; j < 4; ++j) {
            const unsigned u = (unsigned)(v[j] - base);
            if (u < (unsigned)NHALF)
                atomicAdd(&h[u >> 2], 1u << (8 * (u & 3)));  // LDS atomic
        }
    }

    __syncthreads();

    // stream partial to global, 16B stores (HWORDS_H/4 = 3125 uint4)
    uint4* __restrict__ dst = (uint4*)(part + blockIdx.x * HWORDS_H);
    for (int i = threadIdx.x; i < HWORDS_H / 4; i += 1024) dst[i] = h4[i];
}

// Block = 256 threads = 4 waves; block handles 64 nodes.
//   lane (tid & 63) -> OUTPUT o; wave wv -> nodes [16wv, 16wv+16).
// W[o][*] in 64 VGPRs/lane (no scalar loads, no per-FMA LDS); x read via
// wave-uniform global b128 loads (1 transaction each); stores contiguous.
__global__ __launch_bounds__(256, 4) void proj_kernel(
        const float* __restrict__ nf,       // [N_NODES, 64]
        const float* __restrict__ Wn,       // [64, 64] row-major
        const float* __restrict__ bn,       // [64]
        const unsigned* __restrict__ part,  // [HIST_BLOCKS][HWORDS_H]
        float* __restrict__ out) {          // [N_NODES, 64]
    __shared__ __align__(16) float wl[64 * 68];  // pad 68: b128-aligned,
                                                 // conflict-free read/write
    __shared__ unsigned cnt_p[4][64];            // merge-fold partials

    const int t = threadIdx.x;
    const int base = blockIdx.x * 64;
    const int lane = t & 63;
    const int wv = __builtin_amdgcn_readfirstlane(t >> 6);  // 0..3

    // ---- stage W: coalesced global -> padded LDS ----
    {
        const int r = t >> 2;          // 0..63
        const int c0 = (t & 3) * 16;   // 0,16,32,48
#pragma unroll
        for (int k = 0; k < 4; ++k) {
            const float4 v = *reinterpret_cast<const float4*>(
                Wn + r * D + c0 + k * 4);
            *reinterpret_cast<float4*>(&wl[r * 68 + c0 + k * 4]) = v;
        }
    }

    // ---- merge-fold: wave wv sums slice-partials [16wv,16wv+16) for its
    //      lane's node (clamped on tail; unused there). ----
    {
        const int node = min(base + lane, N_NODES - 1);
        const int half = (node >= NHALF) ? 1 : 0;
        const int lw = (node - half * NHALF) >> 2;
        const int sh = 8 * (node & 3);
        unsigned s = 0;
#pragma unroll
        for (int k = 0; k < 16; ++k) {
            const int b = 16 * wv + k;  // slice
            s += (part[(size_t)(2 * b + half) * HWORDS_H + lw] >> sh) & 255u;
        }
        cnt_p[wv][lane] = s;
    }

    __syncthreads();

    // ---- compute ----
    const float blane = bn[lane];  // coalesced, once

    float wr[64];  // this lane's W row; 16 conflict-free ds_read_b128
#pragma unroll
    for (int q = 0; q < 16; ++q) {
        const float4 v = *reinterpret_cast<const float4*>(&wl[lane * 68 + q * 4]);
        wr[q * 4 + 0] = v.x;
        wr[q * 4 + 1] = v.y;
        wr[q * 4 + 2] = v.z;
        wr[q * 4 + 3] = v.w;
    }

#pragma unroll
    for (int g = 0; g < 4; ++g) {
        const int nA = wv * 16 + g * 4;  // first of 4 nodes this group
        const int n0 = min(base + nA + 0, N_NODES - 1);
        const int n1 = min(base + nA + 1, N_NODES - 1);
        const int n2 = min(base + nA + 2, N_NODES - 1);
        const int n3 = min(base + nA + 3, N_NODES - 1);
        // wave-uniform row pointers -> uniform global b128 loads (1 txn each)
        const float* __restrict__ x0 = nf + (size_t)n0 * D;
        const float* __restrict__ x1 = nf + (size_t)n1 * D;
        const float* __restrict__ x2 = nf + (size_t)n2 * D;
        const float* __restrict__ x3 = nf + (size_t)n3 * D;
        float a0 = blane, a1 = blane, a2 = blane, a3 = blane;
#pragma unroll
        for (int q = 0; q < 16; ++q) {
            const float4 v0 = *reinterpret_cast<const float4*>(x0 + q * 4);
            const float4 v1 = *reinterpret_cast<const float4*>(x1 + q * 4);
            const float4 v2 = *reinterpret_cast<const float4*>(x2 + q * 4);
            const float4 v3 = *reinterpret_cast<const float4*>(x3 + q * 4);
            a0 = fmaf(v0.x, wr[q * 4 + 0], a0);
            a0 = fmaf(v0.y, wr[q * 4 + 1], a0);
            a0 = fmaf(v0.z, wr[q * 4 + 2], a0);
            a0 = fmaf(v0.w, wr[q * 4 + 3], a0);
            a1 = fmaf(v1.x, wr[q * 4 + 0], a1);
            a1 = fmaf(v1.y, wr[q * 4 + 1], a1);
            a1 = fmaf(v1.z, wr[q * 4 + 2], a1);
            a1 = fmaf(v1.w, wr[q * 4 + 3], a1);
            a2 = fmaf(v2.x, wr[q * 4 + 0], a2);
            a2 = fmaf(v2.y, wr[q * 4 + 1], a2);
            a2 = fmaf(v2.z, wr[q * 4 + 2], a2);
            a2 = fmaf(v2.w, wr[q * 4 + 3], a2);
            a3 = fmaf(v3.x, wr[q * 4 + 0], a3);
            a3 = fmaf(v3.y, wr[q * 4 + 1], a3);
            a3 = fmaf(v3.z, wr[q * 4 + 2], a3);
            a3 = fmaf(v3.w, wr[q * 4 + 3], a3);
        }
        // counts (uniform LDS reads) + row-contiguous stores
        const float c0f = (float)(cnt_p[0][nA + 0] + cnt_p[1][nA + 0] +
                                  cnt_p[2][nA + 0] + cnt_p[3][nA + 0]);
        const float c1f = (float)(cnt_p[0][nA + 1] + cnt_p[1][nA + 1] +
                                  cnt_p[2][nA + 1] + cnt_p[3][nA + 1]);
        const float c2f = (float)(cnt_p[0][nA + 2] + cnt_p[1][nA + 2] +
                                  cnt_p[2][nA + 2] + cnt_p[3][nA + 2]);
        const float c3f = (float)(cnt_p[0][nA + 3] + cnt_p[1][nA + 3] +
                                  cnt_p[2][nA + 3] + cnt_p[3][nA + 3]);
        const int nodeA = base + nA;
        if (nodeA + 0 < N_NODES) out[(size_t)(nodeA + 0) * D + lane] = c0f * a0;
        if (nodeA + 1 < N_NODES) out[(size_t)(nodeA + 1) * D + lane] = c1f * a1;
        if (nodeA + 2 < N_NODES) out[(size_t)(nodeA + 2) * D + lane] = c2f * a2;
        if (nodeA + 3 < N_NODES) out[(size_t)(nodeA + 3) * D + lane] = c3f * a3;
    }
}

extern "C" void kernel_launch(void* const* d_in, const int* in_sizes, int n_in,
                              void* d_out, int out_size, void* d_ws, size_t ws_size,
                              hipStream_t stream) {
    const float* nf   = (const float*)d_in[0];  // [100000, 64]
    const int*   eidx = (const int*)d_in[1];    // [2, 800000] int64 or int32
    const float* Wn   = (const float*)d_in[3];  // [64, 64]
    const float* bn   = (const float*)d_in[4];  // [64]
    float* out = (float*)d_out;                 // [100000, 64] f32

    unsigned* part = (unsigned*)d_ws;  // 6.4 MB of slice-partials

    hist_kernel<<<HIST_BLOCKS, 1024, 0, stream>>>(eidx, part);

    proj_kernel<<<(N_NODES + 63) / 64, 256, 0, stream>>>(
        nf, Wn, bn, part, out);
}